// Round 1
// baseline (109.270 us; speedup 1.0000x reference)
//
#include <hip/hip_runtime.h>

#define NCLS 24
#define NB 8
#define NCH 128
#define WLO 128
#define HHI 512
#define WHI 512
#define CELLS (128*128)          // 16384 cells per batch
#define SUBS_PER_BLOCK 2         // 64-cell subtiles per block
#define BLOCKS_PER_B 128         // 16384 / (64*2)

// Main kernel: per (b, cls, ch) weighted sums + per (b, cls) counts.
// Block = 256 threads, handles 2 subtiles of 64 cells each.
__global__ __launch_bounds__(256, 4)
void fm_main(const float* __restrict__ data, const int* __restrict__ label,
             float* __restrict__ sums, float* __restrict__ counts) {
    __shared__ float hist[64][NCLS];      // 6144 B, per-cell class weights
    __shared__ float tile[64 * NCH];      // 32768 B, [cell][ch ^ (cell&31)]

    const int bid = blockIdx.x;
    const int b   = bid >> 7;             // /128
    const int grp = bid & 127;
    const int tid = threadIdx.x;

    // staging decomposition
    const int q   = tid & 15;             // float4 slot within 64-cell row
    const int chb = tid >> 4;             // 0..15 channel base
    // accumulate decomposition
    const int ch2       = tid & 63;       // lane channel (also ch2+64)
    const int cellgroup = tid >> 6;       // wave id 0..3 -> cells 16*cg..16*cg+15

    float acc[NCLS][2];
#pragma unroll
    for (int k = 0; k < NCLS; ++k) { acc[k][0] = 0.f; acc[k][1] = 0.f; }
    float cacc = 0.f;                     // class-count acc for tid<24

    const float* dbase = data  + (size_t)b * NCH * CELLS;
    const int*   lbase = label + (size_t)b * (HHI * WHI);

    for (int s = 0; s < SUBS_PER_BLOCK; ++s) {
        const int sub  = grp * SUBS_PER_BLOCK + s;   // 0..255
        const int y    = sub >> 1;                   // low-res cell row
        const int x0   = (sub & 1) << 6;             // 0 or 64
        const int cb   = y * WLO + x0;               // flat cell base (64 consecutive)

        // ---- issue global data loads early (consumed after label phase) ----
        float4 v[8];
#pragma unroll
        for (int k = 0; k < 8; ++k) {
            const int chh = chb + k * 16;
            v[k] = *reinterpret_cast<const float4*>(dbase + (size_t)chh * CELLS + cb + q * 4);
        }

        // ---- zero hist (1536 floats / 256 thr = 6 each) ----
#pragma unroll
        for (int k = 0; k < 6; ++k) ((float*)hist)[tid + k * 256] = 0.f;

        __syncthreads();

        // ---- label histogram: 4 hi-res rows x 256 cols = 1024 labels ----
        {
            const int r  = tid >> 6;       // hi-res row 0..3 within cell row
            const int cl = tid & 63;       // cell within subtile
            const int4 lv = *reinterpret_cast<const int4*>(
                lbase + (size_t)(4 * y + r) * WHI + x0 * 4 + cl * 4);
            if ((unsigned)lv.x < 24u) atomicAdd(&hist[cl][lv.x], 1.f);
            if ((unsigned)lv.y < 24u) atomicAdd(&hist[cl][lv.y], 1.f);
            if ((unsigned)lv.z < 24u) atomicAdd(&hist[cl][lv.z], 1.f);
            if ((unsigned)lv.w < 24u) atomicAdd(&hist[cl][lv.w], 1.f);
        }

        // ---- write data tile, XOR-swizzled [cell][ch ^ (cell&31)] ----
#pragma unroll
        for (int k = 0; k < 8; ++k) {
            const int chh = chb + k * 16;
            const float* vf = (const float*)&v[k];
#pragma unroll
            for (int j = 0; j < 4; ++j) {
                const int c = q * 4 + j;
                tile[c * NCH + (chh ^ (c & 31))] = vf[j];
            }
        }

        __syncthreads();

        // ---- per-class counts: threads 0..23 reduce hist columns ----
        if (tid < NCLS) {
            float cs = 0.f;
#pragma unroll 8
            for (int c = 0; c < 64; ++c) cs += hist[c][tid];
            cacc += cs;
        }

        // ---- accumulate: wave owns 16 cells, 64 lanes span channels ----
#pragma unroll
        for (int ci = 0; ci < 16; ++ci) {
            const int c = cellgroup * 16 + ci;
            const int base = c * NCH + (ch2 ^ (c & 31));
            const float d0 = tile[base];
            const float d1 = tile[base + 64];          // (ch2+64)^(c&31) == base+64
            const float4* wr = reinterpret_cast<const float4*>(&hist[c][0]);
#pragma unroll
            for (int k6 = 0; k6 < 6; ++k6) {
                const float4 w = wr[k6];
                acc[k6 * 4 + 0][0] += w.x * d0;  acc[k6 * 4 + 0][1] += w.x * d1;
                acc[k6 * 4 + 1][0] += w.y * d0;  acc[k6 * 4 + 1][1] += w.y * d1;
                acc[k6 * 4 + 2][0] += w.z * d0;  acc[k6 * 4 + 2][1] += w.z * d1;
                acc[k6 * 4 + 3][0] += w.w * d0;  acc[k6 * 4 + 3][1] += w.w * d1;
            }
        }

        __syncthreads();   // protect hist/tile before next subtile overwrite
    }

    // ---- flush partial sums (coalesced-address atomics) ----
    float* srow = sums + (size_t)b * NCLS * NCH;
#pragma unroll
    for (int k = 0; k < NCLS; ++k) {
        atomicAdd(&srow[k * NCH + ch2],      acc[k][0]);
        atomicAdd(&srow[k * NCH + ch2 + 64], acc[k][1]);
    }
    if (tid < NCLS) atomicAdd(&counts[b * NCLS + tid], cacc);
}

// Finalize: feature[b][ch][cls] = sums[b][cls][ch] / (counts+1e-8); mask = counts>0
__global__ void fm_final(const float* __restrict__ sums,
                         const float* __restrict__ counts,
                         float* __restrict__ out) {
    const int i = blockIdx.x * 256 + threadIdx.x;
    const int NF = NB * NCH * NCLS;   // 24576
    if (i < NF) {
        const int cls = i % NCLS;
        const int t   = i / NCLS;     // b*128 + ch
        const int b   = t >> 7;
        const int ch  = t & 127;
        const float cnt = counts[b * NCLS + cls];
        out[i] = sums[((size_t)b * NCLS + cls) * NCH + ch] / (cnt + 1e-8f);
    } else if (i < NF + NB * NCLS) {
        const int j = i - NF;
        out[i] = counts[j] > 0.f ? 1.f : 0.f;
    }
}

extern "C" void kernel_launch(void* const* d_in, const int* in_sizes, int n_in,
                              void* d_out, int out_size, void* d_ws, size_t ws_size,
                              hipStream_t stream) {
    const float* data  = (const float*)d_in[0];
    const int*   label = (const int*)d_in[1];
    float* out    = (float*)d_out;
    float* sums   = (float*)d_ws;            // 24576 floats
    float* counts = sums + NB * NCLS * NCH;  // 192 floats

    hipMemsetAsync(d_ws, 0, (size_t)(NB * NCLS * NCH + NB * NCLS) * sizeof(float), stream);

    fm_main<<<dim3(NB * BLOCKS_PER_B), dim3(256), 0, stream>>>(data, label, sums, counts);

    const int total = NB * NCH * NCLS + NB * NCLS;   // 24768
    fm_final<<<dim3((total + 255) / 256), dim3(256), 0, stream>>>(sums, counts, out);
}

// Round 2
// 75.128 us; speedup vs baseline: 1.4545x; 1.4545x over previous
//
#include <hip/hip_runtime.h>

#define NCLS 24
#define NB 8
#define NCH 128
#define WLO 128
#define HHI 512
#define WHI 512
#define CELLS (128*128)          // 16384 cells per batch
#define SUBS_PER_BLOCK 4         // 64-cell subtiles per block
#define BLOCKS_PER_B 64          // 16384 / (64*4)
#define NBLK (NB * BLOCKS_PER_B) // 512
#define KCH (NCLS * NCH)         // 3072 per-block partial size

// Main kernel: per-block partial sums[cls][ch] + counts[cls]. NO global atomics.
__global__ __launch_bounds__(256, 3)
void fm_main(const float* __restrict__ data, const int* __restrict__ label,
             float* __restrict__ part, float* __restrict__ cpart) {
    __shared__ float smem[4 * KCH];                    // 49152 B
    float (*hist)[NCLS] = (float (*)[NCLS])smem;       // 64*24 floats
    float* tile = smem + 64 * NCLS;                    // 8192 floats, [cell][ch^ (cell&31)]

    const int bid = blockIdx.x;
    const int b   = bid / BLOCKS_PER_B;
    const int grp = bid % BLOCKS_PER_B;
    const int tid = threadIdx.x;

    // staging decomposition
    const int q   = tid & 15;             // float4 slot within 64-cell row
    const int chb = tid >> 4;             // 0..15 channel base
    // accumulate decomposition
    const int ch2       = tid & 63;       // lane channel (also ch2+64)
    const int cellgroup = tid >> 6;       // wave id 0..3 -> cells 16*cg..16*cg+15

    float acc[NCLS][2];
#pragma unroll
    for (int k = 0; k < NCLS; ++k) { acc[k][0] = 0.f; acc[k][1] = 0.f; }
    float cacc = 0.f;                     // class-count acc for tid<24

    const float* dbase = data  + (size_t)b * NCH * CELLS;
    const int*   lbase = label + (size_t)b * (HHI * WHI);

    for (int s = 0; s < SUBS_PER_BLOCK; ++s) {
        const int sub  = grp * SUBS_PER_BLOCK + s;   // 0..255
        const int y    = sub >> 1;                   // low-res cell row
        const int x0   = (sub & 1) << 6;             // 0 or 64
        const int cb   = y * WLO + x0;               // flat cell base (64 consecutive)

        // ---- issue global data loads early (consumed after label phase) ----
        float4 v[8];
#pragma unroll
        for (int k = 0; k < 8; ++k) {
            const int chh = chb + k * 16;
            v[k] = *reinterpret_cast<const float4*>(dbase + (size_t)chh * CELLS + cb + q * 4);
        }

        // ---- zero hist (1536 floats / 256 thr = 6 each) ----
#pragma unroll
        for (int k = 0; k < 6; ++k) ((float*)hist)[tid + k * 256] = 0.f;

        __syncthreads();

        // ---- label histogram: 4 hi-res rows x 256 cols = 1024 labels ----
        {
            const int r  = tid >> 6;       // hi-res row 0..3 within cell row
            const int cl = tid & 63;       // cell within subtile
            const int4 lv = *reinterpret_cast<const int4*>(
                lbase + (size_t)(4 * y + r) * WHI + x0 * 4 + cl * 4);
            if ((unsigned)lv.x < 24u) atomicAdd(&hist[cl][lv.x], 1.f);
            if ((unsigned)lv.y < 24u) atomicAdd(&hist[cl][lv.y], 1.f);
            if ((unsigned)lv.z < 24u) atomicAdd(&hist[cl][lv.z], 1.f);
            if ((unsigned)lv.w < 24u) atomicAdd(&hist[cl][lv.w], 1.f);
        }

        // ---- write data tile, XOR-swizzled [cell][ch ^ (cell&31)] ----
#pragma unroll
        for (int k = 0; k < 8; ++k) {
            const int chh = chb + k * 16;
            const float* vf = (const float*)&v[k];
#pragma unroll
            for (int j = 0; j < 4; ++j) {
                const int c = q * 4 + j;
                tile[c * NCH + (chh ^ (c & 31))] = vf[j];
            }
        }

        __syncthreads();

        // ---- per-class counts: threads 0..23 reduce hist columns ----
        if (tid < NCLS) {
            float cs = 0.f;
#pragma unroll 8
            for (int c = 0; c < 64; ++c) cs += hist[c][tid];
            cacc += cs;
        }

        // ---- accumulate: wave owns 16 cells, 64 lanes span channels ----
#pragma unroll
        for (int ci = 0; ci < 16; ++ci) {
            const int c = cellgroup * 16 + ci;
            const int base = c * NCH + (ch2 ^ (c & 31));
            const float d0 = tile[base];
            const float d1 = tile[base + 64];          // (ch2+64)^(c&31) == base+64
            const float4* wr = reinterpret_cast<const float4*>(&hist[c][0]);
#pragma unroll
            for (int k6 = 0; k6 < 6; ++k6) {
                const float4 w = wr[k6];
                acc[k6 * 4 + 0][0] += w.x * d0;  acc[k6 * 4 + 0][1] += w.x * d1;
                acc[k6 * 4 + 1][0] += w.y * d0;  acc[k6 * 4 + 1][1] += w.y * d1;
                acc[k6 * 4 + 2][0] += w.z * d0;  acc[k6 * 4 + 2][1] += w.z * d1;
                acc[k6 * 4 + 3][0] += w.w * d0;  acc[k6 * 4 + 3][1] += w.w * d1;
            }
        }

        __syncthreads();   // protect hist/tile before next subtile overwrite
    }

    // ---- cross-wave reduction in LDS (reuse smem), then non-atomic flush ----
    const int w = cellgroup;               // wave id 0..3
    float* red = smem;                     // 4 * 3072 floats
#pragma unroll
    for (int k = 0; k < NCLS; ++k) {
        red[w * KCH + k * NCH + ch2]      = acc[k][0];
        red[w * KCH + k * NCH + ch2 + 64] = acc[k][1];
    }
    // counts: wave 0 threads 0..23 stash before overwrite is fine (cacc in regs)
    __syncthreads();

    float* pblk = part + (size_t)bid * KCH;
#pragma unroll
    for (int kk = 0; kk < 6; ++kk) {
        const int k = w * 6 + kk;
        float s0 = 0.f, s1 = 0.f;
#pragma unroll
        for (int wv = 0; wv < 4; ++wv) {
            s0 += red[wv * KCH + k * NCH + ch2];
            s1 += red[wv * KCH + k * NCH + ch2 + 64];
        }
        pblk[k * NCH + ch2]      = s0;
        pblk[k * NCH + ch2 + 64] = s1;
    }
    if (tid < NCLS) cpart[bid * NCLS + tid] = cacc;
}

// Finalize: reduce per-block partials; feature[b][ch][cls] = sum/(cnt+1e-8); mask.
__global__ void fm_final(const float* __restrict__ part,
                         const float* __restrict__ cpart,
                         float* __restrict__ out) {
    const int t = blockIdx.x * 256 + threadIdx.x;
    const int NF = NB * NCH * NCLS;   // 24576
    if (t < NF) {
        // t = b*3072 + cls*128 + ch  -> coalesced partial reads
        const int b   = t / KCH;
        const int rem = t - b * KCH;
        const int cls = rem >> 7;
        const int ch  = rem & 127;
        float s = 0.f;
        float cnt = 0.f;
        const float* pb = part  + (size_t)b * BLOCKS_PER_B * KCH + rem;
        const float* cb = cpart + (size_t)b * BLOCKS_PER_B * NCLS + cls;
#pragma unroll 8
        for (int g = 0; g < BLOCKS_PER_B; ++g) {
            s   += pb[g * KCH];
            cnt += cb[g * NCLS];
        }
        out[b * KCH + ch * NCLS + cls] = s / (cnt + 1e-8f);
    } else if (t < NF + NB * NCLS) {
        const int j   = t - NF;
        const int b   = j / NCLS;
        const int cls = j - b * NCLS;
        float cnt = 0.f;
        const float* cb = cpart + (size_t)b * BLOCKS_PER_B * NCLS + cls;
#pragma unroll 8
        for (int g = 0; g < BLOCKS_PER_B; ++g) cnt += cb[g * NCLS];
        out[t] = cnt > 0.f ? 1.f : 0.f;
    }
}

extern "C" void kernel_launch(void* const* d_in, const int* in_sizes, int n_in,
                              void* d_out, int out_size, void* d_ws, size_t ws_size,
                              hipStream_t stream) {
    const float* data  = (const float*)d_in[0];
    const int*   label = (const int*)d_in[1];
    float* out   = (float*)d_out;
    float* part  = (float*)d_ws;                       // NBLK * 3072 floats
    float* cpart = part + (size_t)NBLK * KCH;          // NBLK * 24 floats

    fm_main<<<dim3(NBLK), dim3(256), 0, stream>>>(data, label, part, cpart);

    const int total = NB * NCH * NCLS + NB * NCLS;     // 24768
    fm_final<<<dim3((total + 255) / 256), dim3(256), 0, stream>>>(part, cpart, out);
}

// Round 3
// 32.270 us; speedup vs baseline: 3.3861x; 2.3281x over previous
//
#include <hip/hip_runtime.h>

#define NCLS 24
#define NB 8
#define NCH 128
#define WLO 128
#define WHI 512
#define CELLS (128*128)
#define SUBS 2
#define BLOCKS_PER_B (256 / SUBS)   // 128
#define NBLK (NB * BLOCKS_PER_B)    // 1024
#define KCH (NCLS * NCH)            // 3072
#define NF (NB * KCH)               // 24576
#define WPITCH 72                   // f16 pitch: 144B rows -> bank-conflict-free A frags

typedef _Float16 f16x4 __attribute__((ext_vector_type(4)));
typedef _Float16 f16x8 __attribute__((ext_vector_type(8)));
typedef float    f32x4 __attribute__((ext_vector_type(4)));

// Per subtile (64 cells x 128 ch):  sums[32][128] += W[32][64] x T[64][128] via MFMA.
__global__ __launch_bounds__(256, 4)
void fm_main(const float* __restrict__ data, const int* __restrict__ label,
             float* __restrict__ part, float* __restrict__ cpart)
{
    __shared__ unsigned histu[NCLS * 64];     // [cls][cell], 6144 B
    __shared__ _Float16 w16[32 * WPITCH];     // A: [cls(pad32)][cell], 4608 B (rows 24-31 garbage, discarded)
    __shared__ _Float16 tile[NCH * 64];       // B^T: [ch][cell ^ swz], 16384 B

    const int bid  = blockIdx.x;
    const int b    = bid / BLOCKS_PER_B;
    const int grp  = bid % BLOCKS_PER_B;
    const int tid  = threadIdx.x;

    const int q    = tid & 15;        // float4 slot (4 cells)
    const int chb  = tid >> 4;        // channel base 0..15
    const int r    = tid >> 6;        // label hi-res row 0..3
    const int cl   = tid & 63;        // label cell 0..63
    const int w    = tid >> 6;        // wave id
    const int lane = tid & 63;

    const float* dbase = data  + (size_t)b * NCH * CELLS;
    const int*   lbase = label + (size_t)b * (WHI * WHI);

    f32x4 acc[2][2];
#pragma unroll
    for (int mt = 0; mt < 2; ++mt)
#pragma unroll
        for (int nt = 0; nt < 2; ++nt) acc[mt][nt] = (f32x4){0.f, 0.f, 0.f, 0.f};

    float4 v[8];
    int4 lv;

    // prologue: loads for s=0
    {
        const int sub = grp * SUBS;
        const int y = sub >> 1, x0 = (sub & 1) << 6;
        const int cb = y * WLO + x0;
#pragma unroll
        for (int k = 0; k < 8; ++k)
            v[k] = *reinterpret_cast<const float4*>(dbase + (size_t)(chb + k * 16) * CELLS + cb + q * 4);
        lv = *reinterpret_cast<const int4*>(lbase + (size_t)(4 * y + r) * WHI + x0 * 4 + cl * 4);
    }

    unsigned cacc = 0;

#pragma unroll
    for (int s = 0; s < SUBS; ++s) {
        // ---- Phase A: zero hist | barrier | hist atomics + stage f16 tile ----
#pragma unroll
        for (int k = 0; k < 6; ++k) histu[tid + k * 256] = 0u;
        __syncthreads();

        if ((unsigned)lv.x < 24u) atomicAdd(&histu[lv.x * 64 + cl], 1u);
        if ((unsigned)lv.y < 24u) atomicAdd(&histu[lv.y * 64 + cl], 1u);
        if ((unsigned)lv.z < 24u) atomicAdd(&histu[lv.z * 64 + cl], 1u);
        if ((unsigned)lv.w < 24u) atomicAdd(&histu[lv.w * 64 + cl], 1u);

#pragma unroll
        for (int k = 0; k < 8; ++k) {
            const int ch = chb + k * 16;
            f16x4 hv;
            hv[0] = (_Float16)v[k].x; hv[1] = (_Float16)v[k].y;
            hv[2] = (_Float16)v[k].z; hv[3] = (_Float16)v[k].w;
            // cell c = q*4+j stored at ch*64 + (((c>>3)^(ch&7))<<3) + (c&7)
            const int idx = ch * 64 + ((((q >> 1) ^ (ch & 7)) << 3) | ((q & 1) << 2));
            *reinterpret_cast<f16x4*>(&tile[idx]) = hv;
        }
        __syncthreads();

        // ---- Phase B: prefetch s+1, build W (u32->f16), count partials ----
        if (s + 1 < SUBS) {
            const int sub = grp * SUBS + s + 1;
            const int y = sub >> 1, x0 = (sub & 1) << 6;
            const int cb = y * WLO + x0;
#pragma unroll
            for (int k = 0; k < 8; ++k)
                v[k] = *reinterpret_cast<const float4*>(dbase + (size_t)(chb + k * 16) * CELLS + cb + q * 4);
            lv = *reinterpret_cast<const int4*>(lbase + (size_t)(4 * y + r) * WHI + x0 * 4 + cl * 4);
        }

#pragma unroll
        for (int k = 0; k < 6; ++k) {
            const int e = tid + k * 256;
            const int cls = e >> 6, c = e & 63;
            w16[cls * WPITCH + c] = (_Float16)(float)histu[e];   // counts <=16, exact
        }
        if (tid < 96) {
            const int cls = tid >> 2, qq = tid & 3;
#pragma unroll
            for (int i = 0; i < 16; ++i)
                cacc += histu[cls * 64 + qq * 16 + ((i + cls) & 15)];  // rotated: no bank pile-up
        }
        __syncthreads();

        // ---- Phase C: fragment reads + 8 MFMAs per wave ----
        f16x8 af[2][2], bf[2][2];
#pragma unroll
        for (int mt = 0; mt < 2; ++mt)
#pragma unroll
            for (int kt = 0; kt < 2; ++kt)
                af[mt][kt] = *reinterpret_cast<const f16x8*>(
                    &w16[(mt * 16 + (lane & 15)) * WPITCH + kt * 32 + (lane >> 4) * 8]);
#pragma unroll
        for (int nt = 0; nt < 2; ++nt)
#pragma unroll
            for (int kt = 0; kt < 2; ++kt) {
                const int row = w * 32 + nt * 16 + (lane & 15);
                const int g   = kt * 4 + (lane >> 4);
                bf[nt][kt] = *reinterpret_cast<const f16x8*>(
                    &tile[row * 64 + ((g ^ (row & 7)) << 3)]);
            }
#pragma unroll
        for (int mt = 0; mt < 2; ++mt)
#pragma unroll
            for (int nt = 0; nt < 2; ++nt)
#pragma unroll
                for (int kt = 0; kt < 2; ++kt)
                    acc[mt][nt] = __builtin_amdgcn_mfma_f32_16x16x32_f16(
                        af[mt][kt], bf[nt][kt], acc[mt][nt], 0, 0, 0);
        __syncthreads();   // protect tile/w16/histu before next subtile
    }

    // ---- flush per-block partials (non-atomic) ----
    float* pblk = part + (size_t)bid * KCH;
#pragma unroll
    for (int mt = 0; mt < 2; ++mt)
#pragma unroll
        for (int nt = 0; nt < 2; ++nt)
#pragma unroll
            for (int rg = 0; rg < 4; ++rg) {
                const int cls = mt * 16 + (lane >> 4) * 4 + rg;   // C/D: row=(lane>>4)*4+reg
                const int ch  = w * 32 + nt * 16 + (lane & 15);   //       col=lane&15
                if (cls < NCLS) pblk[cls * NCH + ch] = acc[mt][nt][rg];
            }
    if (tid < 96) cpart[(size_t)bid * 96 + tid] = (float)cacc;
}

// One block per (b, cls): reduce 128 block-partials + counts, divide, store.
__global__ __launch_bounds__(256)
void fm_final(const float* __restrict__ part, const float* __restrict__ cpart,
              float* __restrict__ out)
{
    __shared__ float cred[128];
    const int b   = blockIdx.x / NCLS;
    const int cls = blockIdx.x % NCLS;
    const int t   = threadIdx.x;

    float s = 0.f;
    if (t < 128) {
        const float* pb = part + (size_t)(b * BLOCKS_PER_B) * KCH + cls * NCH + t;
#pragma unroll 4
        for (int g = 0; g < BLOCKS_PER_B; ++g) s += pb[(size_t)g * KCH];
    } else {
        const int g = t - 128;
        const float* cb = cpart + (size_t)(b * BLOCKS_PER_B + g) * 96 + cls * 4;
        cred[g] = cb[0] + cb[1] + cb[2] + cb[3];
    }
    __syncthreads();
#pragma unroll
    for (int st = 64; st >= 1; st >>= 1) {
        if (t >= 128 && (t - 128) < st) cred[t - 128] += cred[t - 128 + st];
        __syncthreads();
    }
    const float cnt = cred[0];
    if (t < 128) out[(size_t)b * KCH + t * NCLS + cls] = s / (cnt + 1e-8f);  // (B,C,NCLS)
    if (t == 128) out[NF + b * NCLS + cls] = (cnt > 0.f) ? 1.f : 0.f;        // mask
}

extern "C" void kernel_launch(void* const* d_in, const int* in_sizes, int n_in,
                              void* d_out, int out_size, void* d_ws, size_t ws_size,
                              hipStream_t stream) {
    const float* data  = (const float*)d_in[0];
    const int*   label = (const int*)d_in[1];
    float* out   = (float*)d_out;
    float* part  = (float*)d_ws;                       // NBLK * 3072 floats (12.6 MB)
    float* cpart = part + (size_t)NBLK * KCH;          // NBLK * 96 floats

    fm_main<<<dim3(NBLK), dim3(256), 0, stream>>>(data, label, part, cpart);
    fm_final<<<dim3(NB * NCLS), dim3(256), 0, stream>>>(part, cpart, out);
}